// Round 1
// baseline (84.327 us; speedup 1.0000x reference)
//
#include <hip/hip_runtime.h>

#define MARGIN 0.5f
#define EPS 1e-6f
#define D 256

// Zero the scalar output (d_out is poisoned 0xAA before timing and never
// re-poisoned between graph replays — we must re-init every call).
__global__ void et_zero_kernel(float* __restrict__ out) {
    out[0] = 0.0f;
}

// One wave (64 lanes) per row per iteration: lane i owns columns [4i, 4i+4).
// 64 lanes x float4 = 256 floats = one full row, perfectly coalesced.
__global__ __launch_bounds__(256) void et_triplet_kernel(
        const float* __restrict__ x,
        const float* __restrict__ y,
        const float* __restrict__ z,
        float* __restrict__ out,
        int n_rows) {
    const int lane   = threadIdx.x & 63;
    const int wib    = threadIdx.x >> 6;               // wave index in block (0..3)
    const int wave   = blockIdx.x * 4 + wib;
    const int nwaves = gridDim.x * 4;

    float acc = 0.0f;

    for (int row = wave; row < n_rows; row += nwaves) {
        const size_t base = (size_t)row * D + (size_t)lane * 4;
        const float4 xv = *reinterpret_cast<const float4*>(x + base);
        const float4 yv = *reinterpret_cast<const float4*>(y + base);
        const float4 zv = *reinterpret_cast<const float4*>(z + base);

        float dp, dn;
        {
            float d0 = xv.x - yv.x + EPS;
            float d1 = xv.y - yv.y + EPS;
            float d2 = xv.z - yv.z + EPS;
            float d3 = xv.w - yv.w + EPS;
            dp = d0 * d0 + d1 * d1 + d2 * d2 + d3 * d3;
        }
        {
            float e0 = xv.x - zv.x + EPS;
            float e1 = xv.y - zv.y + EPS;
            float e2 = xv.z - zv.z + EPS;
            float e3 = xv.w - zv.w + EPS;
            dn = e0 * e0 + e1 * e1 + e2 * e2 + e3 * e3;
        }

        // 64-lane butterfly: every lane ends with the full row sums.
        #pragma unroll
        for (int off = 32; off > 0; off >>= 1) {
            dp += __shfl_xor(dp, off, 64);
            dn += __shfl_xor(dn, off, 64);
        }

        const float hinge = sqrtf(dp) + MARGIN - sqrtf(dn);
        if (hinge > 0.0f) acc += hinge;   // wave-uniform value
    }

    // Per-block reduction: one word per wave, one atomic per block.
    __shared__ float wsum[4];
    if (lane == 0) wsum[wib] = acc;
    __syncthreads();
    if (threadIdx.x == 0) {
        const float s = wsum[0] + wsum[1] + wsum[2] + wsum[3];
        atomicAdd(out, s);
    }
}

extern "C" void kernel_launch(void* const* d_in, const int* in_sizes, int n_in,
                              void* d_out, int out_size, void* d_ws, size_t ws_size,
                              hipStream_t stream) {
    const float* x = (const float*)d_in[0];
    const float* y = (const float*)d_in[1];
    const float* z = (const float*)d_in[2];
    float* out = (float*)d_out;

    const int n_rows = in_sizes[0] / D;   // 131072

    et_zero_kernel<<<1, 1, 0, stream>>>(out);

    const int blocks = 2048;              // 8192 waves, 16 rows/wave grid-stride
    et_triplet_kernel<<<blocks, 256, 0, stream>>>(x, y, z, out, n_rows);
}